// Round 5
// baseline (733.992 us; speedup 1.0000x reference)
//
#include <hip/hip_runtime.h>

// Graph unpooling: out[dst[e], :] += edge_attr[e] * x[src[e], :]
// R5: bucket-partition + LDS accumulate. R4's k_scatter was HBM partial-line
// write-bound (51.2MB actual for 6.4MB payload = 800K x 64B lines, 78us).
// New plan: k_part appends edges into 64-row dst-range buckets (dense,
// full-line writes), k_bucket_accum accumulates each bucket in a 32KB LDS
// tile via ds_add_f32 and streams out 32KB contiguous. No pairs/counts/rank.
// History: R2 atomics 1342us; R3 full-CSR 277us; R4 bucket-CSR 264us
// (k_scatter 78us write-bound, k_accum <77us).

#define BROWS   64          // fine rows per bucket (32KB LDS tile)
#define BSHIFT  6
#define CAPB    384         // bucket capacity: Poisson(256) mean + 8 sigma
#define OVFCAP  65536

// --- pass 1: partition edges into dst-range buckets -------------------------

__global__ __launch_bounds__(256) void k_part(
    const int* __restrict__ src, const int* __restrict__ dst,
    const float* __restrict__ w,
    int* __restrict__ cursors, int* __restrict__ ovf_cnt,
    int* __restrict__ ovf_idx, int2* __restrict__ ebuf, int E)
{
    int e = blockIdx.x * 256 + threadIdx.x;
    if (e >= E) return;
    int d = dst[e];
    int b = d >> BSHIFT;
    int pos = atomicAdd(&cursors[b], 1);
    if (pos < CAPB) {
        // meta: bits[21:16]=d&63, bits[15:0]=src (<65536). Always >= 0.
        ebuf[(size_t)b * CAPB + pos] =
            make_int2(((d & (BROWS - 1)) << 16) | src[e], __float_as_int(w[e]));
    } else {
        int p = atomicAdd(ovf_cnt, 1);
        if (p < OVFCAP) ovf_idx[p] = e;
    }
}

// --- pass 2: per-bucket LDS accumulation + streaming store -------------------

__global__ __launch_bounds__(256) void k_bucket_accum(
    const float* __restrict__ x, const int* __restrict__ cursors,
    const int2* __restrict__ ebuf, float* __restrict__ out, int N)
{
    __shared__ float acc[BROWS * 128];          // 32 KB
    const int t = threadIdx.x;
    const int b = blockIdx.x;

    float4* acc4 = reinterpret_cast<float4*>(acc);
    #pragma unroll
    for (int k = 0; k < (BROWS * 32) / 256; ++k)
        acc4[k * 256 + t] = make_float4(0.f, 0.f, 0.f, 0.f);
    __syncthreads();

    int cnt = cursors[b];
    if (cnt > CAPB) cnt = CAPB;

    const int lane = t & 63;
    const int wid  = t >> 6;
    const int2* eb = ebuf + (size_t)b * CAPB;
    const float2* x2 = reinterpret_cast<const float2*>(x);

    // One edge per wave (64 lanes x float2 = full 512B row), 4-deep ILP.
    for (int j0 = wid * 4; j0 < cnt; j0 += 16) {
        int2 m[4];
        #pragma unroll
        for (int u = 0; u < 4; ++u) {
            int j = j0 + u;
            m[u] = (j < cnt) ? eb[j] : make_int2(-1, 0);
        }
        float2 v[4];
        #pragma unroll
        for (int u = 0; u < 4; ++u) {
            if (m[u].x >= 0)
                v[u] = x2[((size_t)(m[u].x & 0xFFFF) << 6) + lane];
        }
        #pragma unroll
        for (int u = 0; u < 4; ++u) {
            if (m[u].x >= 0) {
                float wgt = __int_as_float(m[u].y);
                float* a = acc + (m[u].x >> 16) * 128 + lane * 2;
                atomicAdd(a + 0, wgt * v[u].x);   // ds_add_f32, 2-way bank (free)
                atomicAdd(a + 1, wgt * v[u].y);
            }
        }
    }
    __syncthreads();

    // Stream 64 rows x 512B contiguous. Rows with no edges write zeros.
    float4* out4 = reinterpret_cast<float4*>(out);
    size_t base4 = (size_t)b * (BROWS * 32);
    int rows_left = N - b * BROWS;              // N=200000 is 3125*64 exactly
    int flat_max = (rows_left >= BROWS ? BROWS * 32 : rows_left * 32);
    #pragma unroll
    for (int k = 0; k < (BROWS * 32) / 256; ++k) {
        int f4 = k * 256 + t;
        if (f4 < flat_max) out4[base4 + f4] = acc4[f4];
    }
}

// --- pass 3: rare bucket-overflow edges, atomic into out ---------------------

__global__ __launch_bounds__(256) void k_overflow(
    const float* __restrict__ x, const int* __restrict__ src,
    const int* __restrict__ dst, const float* __restrict__ w,
    const int* __restrict__ ovf_cnt, const int* __restrict__ ovf_idx,
    float* __restrict__ out)
{
    int novf = *ovf_cnt;
    if (novf > OVFCAP) novf = OVFCAP;
    long total = (long)novf * 32;
    long stride = (long)gridDim.x * 256;
    for (long i = (long)blockIdx.x * 256 + threadIdx.x; i < total; i += stride) {
        int k = (int)(i >> 5);
        int q = (int)(i & 31);
        int e = ovf_idx[k];
        float ww = w[e];
        float4 v = reinterpret_cast<const float4*>(x)[((long)src[e] << 5) + q];
        float* o = out + ((long)dst[e] << 7) + (q << 2);
        atomicAdd(o + 0, v.x * ww); atomicAdd(o + 1, v.y * ww);
        atomicAdd(o + 2, v.z * ww); atomicAdd(o + 3, v.w * ww);
    }
}

// --- fallback: R2 atomic baseline (ws too small) -----------------------------

__global__ __launch_bounds__(256) void unpool_scatter_atomic(
    const float* __restrict__ x, const int* __restrict__ src_idx,
    const int* __restrict__ dst_idx, const float* __restrict__ edge_attr,
    float* __restrict__ out, int E)
{
    long tid = (long)blockIdx.x * (long)blockDim.x + threadIdx.x;
    int e = (int)(tid >> 5);
    if (e >= E) return;
    int q = (int)(tid & 31);
    float w = edge_attr[e];
    const float4 v = reinterpret_cast<const float4*>(x)[((long)src_idx[e] << 5) + q];
    float* o = out + ((long)dst_idx[e] << 7) + (q << 2);
    atomicAdd(o + 0, v.x * w); atomicAdd(o + 1, v.y * w);
    atomicAdd(o + 2, v.z * w); atomicAdd(o + 3, v.w * w);
}

extern "C" void kernel_launch(void* const* d_in, const int* in_sizes, int n_in,
                              void* d_out, int out_size, void* d_ws, size_t ws_size,
                              hipStream_t stream) {
    const float* x        = (const float*)d_in[0];
    const int*   src_idx  = (const int*)d_in[1];
    const int*   dst_idx  = (const int*)d_in[2];
    const float* edge_att = (const float*)d_in[3];
    float*       out      = (float*)d_out;

    const int E = in_sizes[1];          // 800000
    const int C = 128;
    const int N = out_size / C;         // 200000
    const int NBUC = (N + BROWS - 1) >> BSHIFT;   // 3125

    // ws layout: cursors | ovf_cnt | ovf_idx | ebuf
    size_t off_ovfcnt = ((size_t)NBUC * 4 + 15) & ~(size_t)15;
    size_t off_ovfidx = off_ovfcnt + 16;
    size_t off_ebuf   = (off_ovfidx + (size_t)OVFCAP * 4 + 15) & ~(size_t)15;
    size_t need       = off_ebuf + (size_t)NBUC * CAPB * 8;

    if (ws_size < need) {
        hipMemsetAsync(d_out, 0, (size_t)out_size * sizeof(float), stream);
        long total = (long)E * 32;
        unpool_scatter_atomic<<<dim3((unsigned)((total + 255) / 256)), dim3(256),
                                0, stream>>>(x, src_idx, dst_idx, edge_att, out, E);
        return;
    }

    char* ws = (char*)d_ws;
    int*  cursors = (int*)(ws);
    int*  ovf_cnt = (int*)(ws + off_ovfcnt);
    int*  ovf_idx = (int*)(ws + off_ovfidx);
    int2* ebuf    = (int2*)(ws + off_ebuf);

    // Zero cursors + overflow counter in one small memset (13 KB).
    hipMemsetAsync(ws, 0, off_ovfcnt + 16, stream);

    k_part<<<dim3((E + 255) / 256), dim3(256), 0, stream>>>(
        src_idx, dst_idx, edge_att, cursors, ovf_cnt, ovf_idx, ebuf, E);

    k_bucket_accum<<<dim3(NBUC), dim3(256), 0, stream>>>(
        x, cursors, ebuf, out, N);

    k_overflow<<<dim3(256), dim3(256), 0, stream>>>(
        x, src_idx, dst_idx, edge_att, ovf_cnt, ovf_idx, out);
}

// Round 6
// 698.844 us; speedup vs baseline: 1.0503x; 1.0503x over previous
//
#include <hip/hip_runtime.h>

// Graph unpooling: out[dst[e], :] += edge_attr[e] * x[src[e], :]
// R6: revert R5 (bucket-LDS accum was latency-bound: 12.5K waves, 4-deep ILP
// vs R4's 100K waves x 8-deep -> 563us). Back to R4 bucket-CSR + fix the real
// wall: k_scatter's partial-line writes (51MB HBM for 6.4MB payload, 78us).
// Fix: XCD-windowed scatter. dst-space split into 8 windows of 25K rows;
// pairs window = 1.6MB -> resident in one XCD's 4MB L2, so a 64B line
// collects all its records before eviction. Blocks read their physical XCD id
// (s_getreg HW_REG_XCC_ID, id=20) and drain their own window first, then
// steal others -> correct for ANY xcc value (all cursors always drained).
// History: R2 atomics 1342us; R3 full-CSR 277us; R4 bucket-CSR 264us
// (scatter 78 write-bound, accum <=77); R5 LDS-bucket 734us REGRESSION.

#define NWIN   8
#define CHUNK  2048

// --- pass 1: XCD-windowed rank-and-place ------------------------------------

template<int CAP>
__global__ __launch_bounds__(256) void k_scatter_win(
    const int* __restrict__ src, const int* __restrict__ dst,
    const float* __restrict__ w,
    int* __restrict__ counts, int* __restrict__ chunk_cur,
    int* __restrict__ ovf_cnt, int* __restrict__ ovf_idx,
    int2* __restrict__ pairs, int E, int W)
{
    int xcc;
    asm volatile("s_getreg_b32 %0, hwreg(20, 0, 32)" : "=s"(xcc)); // XCC_ID
    xcc &= (NWIN - 1);
    const int lane = threadIdx.x & 63;

    for (int wo = 0; wo < NWIN; ++wo) {
        int win = (xcc + wo) & (NWIN - 1);
        int lo = win * W;
        int hi = lo + W;                     // d < N always caps last window
        for (;;) {
            int c = 0;
            if (lane == 0) c = atomicAdd(&chunk_cur[win], CHUNK);
            c = __shfl(c, 0);                // wave-broadcast
            if (c >= E) break;
            int end = c + CHUNK; if (end > E) end = E;
            for (int e = c + lane; e < end; e += 64) {
                int d = dst[e];
                if (d >= lo && d < hi) {
                    int r = atomicAdd(&counts[d], 1);
                    if (r < CAP) {
                        pairs[(size_t)d * CAP + r] =
                            make_int2(src[e], __float_as_int(w[e]));
                    } else {
                        int p = atomicAdd(ovf_cnt, 1);
                        ovf_idx[p] = e;
                    }
                }
            }
        }
    }
}

// --- pass 2: per-row register accumulation (R4, proven) ----------------------

template<int CAP>
__global__ __launch_bounds__(256) void k_accum(
    const float* __restrict__ x, const int* __restrict__ counts,
    const int2* __restrict__ pairs, float* __restrict__ out, int N)
{
    long tid = (long)blockIdx.x * 256 + threadIdx.x;
    int row = (int)(tid >> 5);
    if (row >= N) return;
    int q = (int)(tid & 31);

    int cnt = counts[row];
    if (cnt > CAP) cnt = CAP;

    const int4* prow = reinterpret_cast<const int4*>(pairs + (size_t)row * CAP);
    int s[CAP]; float wv[CAP];
    #pragma unroll
    for (int r2 = 0; r2 < CAP / 2; ++r2) {
        int4 pk = prow[r2];
        s[2 * r2]     = pk.x; wv[2 * r2]     = __int_as_float(pk.y);
        s[2 * r2 + 1] = pk.z; wv[2 * r2 + 1] = __int_as_float(pk.w);
    }
    #pragma unroll
    for (int r = 0; r < CAP; ++r)
        if (r >= cnt) wv[r] = 0.f;           // sanitize poison slots

    // Independent predicated gathers — all in flight before accumulation.
    const float4* x4 = reinterpret_cast<const float4*>(x);
    float4 v[CAP];
    #pragma unroll
    for (int r = 0; r < CAP; ++r) {
        v[r] = make_float4(0.f, 0.f, 0.f, 0.f);
        if (r < cnt) v[r] = x4[((long)s[r] << 5) + q];
    }
    float4 acc = make_float4(0.f, 0.f, 0.f, 0.f);
    #pragma unroll
    for (int r = 0; r < CAP; ++r) {
        acc.x += wv[r] * v[r].x; acc.y += wv[r] * v[r].y;
        acc.z += wv[r] * v[r].z; acc.w += wv[r] * v[r].w;
    }
    reinterpret_cast<float4*>(out)[((long)row << 5) + q] = acc;
}

// --- pass 3: rare rank>=CAP edges, atomic on top of stored rows --------------

__global__ __launch_bounds__(256) void k_overflow(
    const float* __restrict__ x, const int* __restrict__ src,
    const int* __restrict__ dst, const float* __restrict__ w,
    const int* __restrict__ ovf_cnt, const int* __restrict__ ovf_idx,
    float* __restrict__ out)
{
    int novf = *ovf_cnt;
    long total = (long)novf * 32;
    long stride = (long)gridDim.x * 256;
    for (long i = (long)blockIdx.x * 256 + threadIdx.x; i < total; i += stride) {
        int k = (int)(i >> 5);
        int q = (int)(i & 31);
        int e = ovf_idx[k];
        float ww = w[e];
        float4 v = reinterpret_cast<const float4*>(x)[((long)src[e] << 5) + q];
        float* o = out + ((long)dst[e] << 7) + (q << 2);
        atomicAdd(o + 0, v.x * ww); atomicAdd(o + 1, v.y * ww);
        atomicAdd(o + 2, v.z * ww); atomicAdd(o + 3, v.w * ww);
    }
}

// --- fallback: R2 atomic baseline (ws too small) -----------------------------

__global__ __launch_bounds__(256) void unpool_scatter_atomic(
    const float* __restrict__ x, const int* __restrict__ src_idx,
    const int* __restrict__ dst_idx, const float* __restrict__ edge_attr,
    float* __restrict__ out, int E)
{
    long tid = (long)blockIdx.x * (long)blockDim.x + threadIdx.x;
    int e = (int)(tid >> 5);
    if (e >= E) return;
    int q = (int)(tid & 31);
    float w = edge_attr[e];
    const float4 v = reinterpret_cast<const float4*>(x)[((long)src_idx[e] << 5) + q];
    float* o = out + ((long)dst_idx[e] << 7) + (q << 2);
    atomicAdd(o + 0, v.x * w); atomicAdd(o + 1, v.y * w);
    atomicAdd(o + 2, v.z * w); atomicAdd(o + 3, v.w * w);
}

template<int CAP>
static void launch_path(const float* x, const int* src_idx, const int* dst_idx,
                        const float* edge_att, float* out, char* ws,
                        int E, int N, int W,
                        size_t off_ccur, size_t off_ovf, size_t off_ovfidx,
                        size_t off_pairs, hipStream_t stream)
{
    int*  counts  = (int*)(ws);
    int*  ccur    = (int*)(ws + off_ccur);
    int*  ovf_cnt = (int*)(ws + off_ovf);
    int*  ovf_idx = (int*)(ws + off_ovfidx);
    int2* pairs   = (int2*)(ws + off_pairs);

    // Zero counts + chunk cursors + overflow counter in one memset (~0.8MB).
    hipMemsetAsync(ws, 0, off_ovf + 16, stream);

    k_scatter_win<CAP><<<dim3(1024), dim3(256), 0, stream>>>(
        src_idx, dst_idx, edge_att, counts, ccur, ovf_cnt, ovf_idx, pairs, E, W);

    long total = (long)N * 32;
    k_accum<CAP><<<dim3((unsigned)((total + 255) / 256)), dim3(256), 0, stream>>>(
        x, counts, pairs, out, N);

    k_overflow<<<dim3(256), dim3(256), 0, stream>>>(
        x, src_idx, dst_idx, edge_att, ovf_cnt, ovf_idx, out);
}

extern "C" void kernel_launch(void* const* d_in, const int* in_sizes, int n_in,
                              void* d_out, int out_size, void* d_ws, size_t ws_size,
                              hipStream_t stream) {
    const float* x        = (const float*)d_in[0];
    const int*   src_idx  = (const int*)d_in[1];
    const int*   dst_idx  = (const int*)d_in[2];
    const float* edge_att = (const float*)d_in[3];
    float*       out      = (float*)d_out;

    const int E = in_sizes[1];          // 800000
    const int C = 128;
    const int N = out_size / C;         // 200000
    const int W = (N + NWIN - 1) / NWIN;

    // ws: counts | chunk_cur | ovf_cnt | ovf_idx | pairs
    size_t off_ccur   = ((size_t)N * 4 + 15) & ~(size_t)15;
    size_t off_ovf    = off_ccur + ((NWIN * 4 + 15) & ~15);
    size_t off_ovfidx = off_ovf + 16;
    size_t off_pairs  = (off_ovfidx + (size_t)E * 4 + 15) & ~(size_t)15;
    size_t need8 = off_pairs + (size_t)N * 8 * 8;
    size_t need4 = off_pairs + (size_t)N * 4 * 8;

    char* ws = (char*)d_ws;
    if (ws_size >= need8) {
        launch_path<8>(x, src_idx, dst_idx, edge_att, out, ws, E, N, W,
                       off_ccur, off_ovf, off_ovfidx, off_pairs, stream);
    } else if (ws_size >= need4) {
        launch_path<4>(x, src_idx, dst_idx, edge_att, out, ws, E, N, W,
                       off_ccur, off_ovf, off_ovfidx, off_pairs, stream);
    } else {
        hipMemsetAsync(d_out, 0, (size_t)out_size * sizeof(float), stream);
        long total = (long)E * 32;
        unpool_scatter_atomic<<<dim3((unsigned)((total + 255) / 256)), dim3(256),
                                0, stream>>>(x, src_idx, dst_idx, edge_att, out, E);
    }
}

// Round 7
// 438.637 us; speedup vs baseline: 1.6733x; 1.5932x over previous
//
#include <hip/hip_runtime.h>
#include <hip/hip_fp16.h>

// Graph unpooling: out[dst[e], :] += edge_attr[e] * x[src[e], :]
// R7 = R4 bucket-CSR base + two independent fixes:
//  (a) scatter: XCD-EXCLUSIVE dst-windows (R6's steal loop destroyed locality;
//      now each XCD scans E once, places only its own 25K-row window; pairs
//      window 1.6MB lives in the home L2; streaming reads are nontemporal so
//      they don't evict the hot write lines). k_scatter_sweep drains leftovers
//      if XCC_ID mapping is ever degenerate -> correctness independent of XCC.
//  (b) accum: x pre-converted to fp16 (k_convert) -> gather demand 410->205MB.
// History: R2 atomics 1342us; R3 full-CSR 277; R4 bucket-CSR 264 (scatter 78
// write-amp 51MB=E*64B, accum ~77); R5 LDS-accum 734 REGR (latency, low MLP);
// R6 windowed+steal 699 REGR (WRITE unchanged, 8x serial scans).

#define NWIN   8
#define CHUNK  512
#define CAP    8

// --- x -> fp16 --------------------------------------------------------------

__global__ __launch_bounds__(256) void k_convert(
    const float* __restrict__ x, __half2* __restrict__ xh, int nf4)
{
    int i = blockIdx.x * 256 + threadIdx.x;
    if (i >= nf4) return;
    float4 v = reinterpret_cast<const float4*>(x)[i];
    xh[2 * i]     = __floats2half2_rn(v.x, v.y);
    xh[2 * i + 1] = __floats2half2_rn(v.z, v.w);
}

// --- pass 1: XCD-exclusive windowed rank-and-place ---------------------------

__global__ __launch_bounds__(256) void k_scatter_win(
    const int* __restrict__ src, const int* __restrict__ dst,
    const float* __restrict__ w,
    int* __restrict__ counts, int* __restrict__ chunk_cur,
    int* __restrict__ ovf_cnt, int* __restrict__ ovf_idx,
    int2* __restrict__ pairs, int E, int W)
{
    int xcc;
    asm volatile("s_getreg_b32 %0, hwreg(20, 0, 32)" : "=s"(xcc)); // XCC_ID
    const int win = xcc & (NWIN - 1);
    const int lo = win * W, hi = lo + W;
    const int lane = threadIdx.x & 63;

    for (;;) {
        int c = 0;
        if (lane == 0) c = atomicAdd(&chunk_cur[win], CHUNK);
        c = __shfl(c, 0);
        if (c >= E) break;
        int end = c + CHUNK; if (end > E) end = E;
        for (int e = c + lane; e < end; e += 64) {
            int d = __builtin_nontemporal_load(dst + e);
            if (d >= lo && d < hi) {
                int   s  = __builtin_nontemporal_load(src + e);
                float ww = __builtin_nontemporal_load(w + e);
                int r = atomicAdd(&counts[d], 1);
                if (r < CAP) {
                    pairs[(size_t)d * CAP + r] = make_int2(s, __float_as_int(ww));
                } else {
                    int p = atomicAdd(ovf_cnt, 1);
                    ovf_idx[p] = e;
                }
            }
        }
    }
}

// Safety net: drains any window the XCC-keyed kernel left unfinished.
// Normal case: 8 cursor probes per wave, immediate exit.
__global__ __launch_bounds__(256) void k_scatter_sweep(
    const int* __restrict__ src, const int* __restrict__ dst,
    const float* __restrict__ w,
    int* __restrict__ counts, int* __restrict__ chunk_cur,
    int* __restrict__ ovf_cnt, int* __restrict__ ovf_idx,
    int2* __restrict__ pairs, int E, int W)
{
    const int lane = threadIdx.x & 63;
    for (int win = 0; win < NWIN; ++win) {
        const int lo = win * W, hi = lo + W;
        for (;;) {
            int c = 0;
            if (lane == 0) c = atomicAdd(&chunk_cur[win], CHUNK);
            c = __shfl(c, 0);
            if (c >= E) break;
            int end = c + CHUNK; if (end > E) end = E;
            for (int e = c + lane; e < end; e += 64) {
                int d = dst[e];
                if (d >= lo && d < hi) {
                    int r = atomicAdd(&counts[d], 1);
                    if (r < CAP) {
                        pairs[(size_t)d * CAP + r] =
                            make_int2(src[e], __float_as_int(w[e]));
                    } else {
                        int p = atomicAdd(ovf_cnt, 1);
                        ovf_idx[p] = e;
                    }
                }
            }
        }
    }
}

// --- pass 2: per-row register accumulation, fp16 gathers ---------------------

__global__ __launch_bounds__(256) void k_accum_h(
    const __half2* __restrict__ xh, const int* __restrict__ counts,
    const int2* __restrict__ pairs, float* __restrict__ out, int N)
{
    long tid = (long)blockIdx.x * 256 + threadIdx.x;
    int row = (int)(tid >> 5);
    if (row >= N) return;
    int q = (int)(tid & 31);

    int cnt = counts[row];
    if (cnt > CAP) cnt = CAP;

    const int4* prow = reinterpret_cast<const int4*>(pairs + (size_t)row * CAP);
    int s[CAP]; float wv[CAP];
    #pragma unroll
    for (int r2 = 0; r2 < CAP / 2; ++r2) {
        int4 pk = prow[r2];
        s[2 * r2]     = pk.x; wv[2 * r2]     = __int_as_float(pk.y);
        s[2 * r2 + 1] = pk.z; wv[2 * r2 + 1] = __int_as_float(pk.w);
    }
    #pragma unroll
    for (int r = 0; r < CAP; ++r)
        if (r >= cnt) wv[r] = 0.f;          // sanitize poison slots

    // Independent predicated gathers: 8B/lane = 4 halves (channels 4q..4q+3).
    const uint2* x2 = reinterpret_cast<const uint2*>(xh);
    uint2 g[CAP];
    #pragma unroll
    for (int r = 0; r < CAP; ++r) {
        g[r] = make_uint2(0u, 0u);
        if (r < cnt) g[r] = x2[((long)s[r] << 5) + q];
    }
    float4 acc = make_float4(0.f, 0.f, 0.f, 0.f);
    #pragma unroll
    for (int r = 0; r < CAP; ++r) {
        float2 f01 = __half22float2(*reinterpret_cast<__half2*>(&g[r].x));
        float2 f23 = __half22float2(*reinterpret_cast<__half2*>(&g[r].y));
        acc.x += wv[r] * f01.x; acc.y += wv[r] * f01.y;
        acc.z += wv[r] * f23.x; acc.w += wv[r] * f23.y;
    }
    reinterpret_cast<float4*>(out)[((long)row << 5) + q] = acc;
}

// f32 accum (fallback when ws can't hold xh) — proven R4 kernel.
__global__ __launch_bounds__(256) void k_accum_f(
    const float* __restrict__ x, const int* __restrict__ counts,
    const int2* __restrict__ pairs, float* __restrict__ out, int N)
{
    long tid = (long)blockIdx.x * 256 + threadIdx.x;
    int row = (int)(tid >> 5);
    if (row >= N) return;
    int q = (int)(tid & 31);
    int cnt = counts[row];
    if (cnt > CAP) cnt = CAP;
    const int4* prow = reinterpret_cast<const int4*>(pairs + (size_t)row * CAP);
    int s[CAP]; float wv[CAP];
    #pragma unroll
    for (int r2 = 0; r2 < CAP / 2; ++r2) {
        int4 pk = prow[r2];
        s[2 * r2]     = pk.x; wv[2 * r2]     = __int_as_float(pk.y);
        s[2 * r2 + 1] = pk.z; wv[2 * r2 + 1] = __int_as_float(pk.w);
    }
    #pragma unroll
    for (int r = 0; r < CAP; ++r)
        if (r >= cnt) wv[r] = 0.f;
    const float4* x4 = reinterpret_cast<const float4*>(x);
    float4 v[CAP];
    #pragma unroll
    for (int r = 0; r < CAP; ++r) {
        v[r] = make_float4(0.f, 0.f, 0.f, 0.f);
        if (r < cnt) v[r] = x4[((long)s[r] << 5) + q];
    }
    float4 acc = make_float4(0.f, 0.f, 0.f, 0.f);
    #pragma unroll
    for (int r = 0; r < CAP; ++r) {
        acc.x += wv[r] * v[r].x; acc.y += wv[r] * v[r].y;
        acc.z += wv[r] * v[r].z; acc.w += wv[r] * v[r].w;
    }
    reinterpret_cast<float4*>(out)[((long)row << 5) + q] = acc;
}

// --- pass 3: rare rank>=CAP edges (f32 x, exact) -----------------------------

__global__ __launch_bounds__(256) void k_overflow(
    const float* __restrict__ x, const int* __restrict__ src,
    const int* __restrict__ dst, const float* __restrict__ w,
    const int* __restrict__ ovf_cnt, const int* __restrict__ ovf_idx,
    float* __restrict__ out)
{
    int novf = *ovf_cnt;
    long total = (long)novf * 32;
    long stride = (long)gridDim.x * 256;
    for (long i = (long)blockIdx.x * 256 + threadIdx.x; i < total; i += stride) {
        int k = (int)(i >> 5);
        int q = (int)(i & 31);
        int e = ovf_idx[k];
        float ww = w[e];
        float4 v = reinterpret_cast<const float4*>(x)[((long)src[e] << 5) + q];
        float* o = out + ((long)dst[e] << 7) + (q << 2);
        atomicAdd(o + 0, v.x * ww); atomicAdd(o + 1, v.y * ww);
        atomicAdd(o + 2, v.z * ww); atomicAdd(o + 3, v.w * ww);
    }
}

// --- fallback: R2 atomic baseline (ws too small) -----------------------------

__global__ __launch_bounds__(256) void unpool_scatter_atomic(
    const float* __restrict__ x, const int* __restrict__ src_idx,
    const int* __restrict__ dst_idx, const float* __restrict__ edge_attr,
    float* __restrict__ out, int E)
{
    long tid = (long)blockIdx.x * (long)blockDim.x + threadIdx.x;
    int e = (int)(tid >> 5);
    if (e >= E) return;
    int q = (int)(tid & 31);
    float w = edge_attr[e];
    const float4 v = reinterpret_cast<const float4*>(x)[((long)src_idx[e] << 5) + q];
    float* o = out + ((long)dst_idx[e] << 7) + (q << 2);
    atomicAdd(o + 0, v.x * w); atomicAdd(o + 1, v.y * w);
    atomicAdd(o + 2, v.z * w); atomicAdd(o + 3, v.w * w);
}

extern "C" void kernel_launch(void* const* d_in, const int* in_sizes, int n_in,
                              void* d_out, int out_size, void* d_ws, size_t ws_size,
                              hipStream_t stream) {
    const float* x        = (const float*)d_in[0];
    const int*   src_idx  = (const int*)d_in[1];
    const int*   dst_idx  = (const int*)d_in[2];
    const float* edge_att = (const float*)d_in[3];
    float*       out      = (float*)d_out;

    const int E  = in_sizes[1];         // 800000
    const int C  = 128;
    const int N  = out_size / C;        // 200000
    const int NC = in_sizes[0] / C;     // 50000 coarse rows
    const int W  = (N + NWIN - 1) / NWIN;

    // ws: counts | chunk_cur | ovf_cnt | ovf_idx | pairs | xh
    size_t off_ccur   = ((size_t)N * 4 + 15) & ~(size_t)15;
    size_t off_ovf    = off_ccur + 64;
    size_t off_ovfidx = off_ovf + 16;
    size_t off_pairs  = (off_ovfidx + (size_t)E * 4 + 15) & ~(size_t)15;
    size_t off_xh     = off_pairs + (size_t)N * CAP * 8;
    size_t need_base  = off_xh;
    size_t need_h     = off_xh + (size_t)NC * C * 2;

    char* ws = (char*)d_ws;
    if (ws_size < need_base) {
        hipMemsetAsync(d_out, 0, (size_t)out_size * sizeof(float), stream);
        long total = (long)E * 32;
        unpool_scatter_atomic<<<dim3((unsigned)((total + 255) / 256)), dim3(256),
                                0, stream>>>(x, src_idx, dst_idx, edge_att, out, E);
        return;
    }

    int*     counts  = (int*)(ws);
    int*     ccur    = (int*)(ws + off_ccur);
    int*     ovf_cnt = (int*)(ws + off_ovf);
    int*     ovf_idx = (int*)(ws + off_ovfidx);
    int2*    pairs   = (int2*)(ws + off_pairs);
    __half2* xh      = (__half2*)(ws + off_xh);
    const bool use_h = (ws_size >= need_h);

    // Zero counts + window cursors + overflow counter (~0.8MB).
    hipMemsetAsync(ws, 0, off_ovf + 16, stream);

    if (use_h) {
        int nf4 = NC * C / 4;
        k_convert<<<dim3((nf4 + 255) / 256), dim3(256), 0, stream>>>(x, xh, nf4);
    }

    k_scatter_win<<<dim3(1024), dim3(256), 0, stream>>>(
        src_idx, dst_idx, edge_att, counts, ccur, ovf_cnt, ovf_idx, pairs, E, W);
    k_scatter_sweep<<<dim3(64), dim3(256), 0, stream>>>(
        src_idx, dst_idx, edge_att, counts, ccur, ovf_cnt, ovf_idx, pairs, E, W);

    long total = (long)N * 32;
    if (use_h) {
        k_accum_h<<<dim3((unsigned)((total + 255) / 256)), dim3(256), 0, stream>>>(
            xh, counts, pairs, out, N);
    } else {
        k_accum_f<<<dim3((unsigned)((total + 255) / 256)), dim3(256), 0, stream>>>(
            x, counts, pairs, out, N);
    }

    k_overflow<<<dim3(256), dim3(256), 0, stream>>>(
        x, src_idx, dst_idx, edge_att, ovf_cnt, ovf_idx, out);
}

// Round 8
// 265.954 us; speedup vs baseline: 2.7598x; 1.6493x over previous
//
#include <hip/hip_runtime.h>
#include <hip/hip_fp16.h>

// Graph unpooling: out[dst[e], :] += edge_attr[e] * x[src[e], :]
// R8 = consolidation: R4 bucket-CSR scatter (best measured, 78us) with
// 2 edges/thread (ILP experiment: latency-bound vs HBM-line-bound), plus
// fp16 x path (R7-proven, absmax 0.0625 <= 0.205): convert ~8us, accum
// gather demand 410->205MB. Windows/sweep dropped (R6/R7 regressions).
// History: R2 atomics 1342; R3 full-CSR 277; R4 bucket-CSR 264 (scatter 78,
// WRITE 51MB=E*64B partial lines; accum ~77); R5 LDS-accum 734 REGR (low
// MLP); R6 steal-windows 699 REGR; R7 excl-windows 439 REGR (8x scans;
// exclusivity did NOT merge lines: WRITE 43MB).

#define CAP    8
#define OVFCAP 65536

// --- x -> fp16 ---------------------------------------------------------------

__global__ __launch_bounds__(256) void k_convert(
    const float* __restrict__ x, __half2* __restrict__ xh, int nf4)
{
    int i = blockIdx.x * 256 + threadIdx.x;
    if (i >= nf4) return;
    float4 v = reinterpret_cast<const float4*>(x)[i];
    xh[2 * i]     = __floats2half2_rn(v.x, v.y);
    xh[2 * i + 1] = __floats2half2_rn(v.z, v.w);
}

// --- pass 1: rank-and-place, 2 edges per thread ------------------------------

__global__ __launch_bounds__(256) void k_scatter(
    const int* __restrict__ src, const int* __restrict__ dst,
    const float* __restrict__ w,
    int* __restrict__ counts, int* __restrict__ ovf_cnt,
    int* __restrict__ ovf_idx, int2* __restrict__ pairs, int E)
{
    int t = blockIdx.x * 256 + threadIdx.x;
    int e0 = 2 * t;
    if (e0 >= E) return;

    if (e0 + 1 < E) {
        // Vector loads for two edges; two independent atomic/store chains.
        int2   d2 = *reinterpret_cast<const int2*>(dst + e0);
        int2   s2 = *reinterpret_cast<const int2*>(src + e0);
        float2 w2 = *reinterpret_cast<const float2*>(w + e0);

        int r0 = atomicAdd(&counts[d2.x], 1);
        int r1 = atomicAdd(&counts[d2.y], 1);
        if (r0 < CAP) {
            pairs[(size_t)d2.x * CAP + r0] = make_int2(s2.x, __float_as_int(w2.x));
        } else {
            int p = atomicAdd(ovf_cnt, 1);
            if (p < OVFCAP) ovf_idx[p] = e0;
        }
        if (r1 < CAP) {
            pairs[(size_t)d2.y * CAP + r1] = make_int2(s2.y, __float_as_int(w2.y));
        } else {
            int p = atomicAdd(ovf_cnt, 1);
            if (p < OVFCAP) ovf_idx[p] = e0 + 1;
        }
    } else {
        int d = dst[e0];
        int r = atomicAdd(&counts[d], 1);
        if (r < CAP) {
            pairs[(size_t)d * CAP + r] = make_int2(src[e0], __float_as_int(w[e0]));
        } else {
            int p = atomicAdd(ovf_cnt, 1);
            if (p < OVFCAP) ovf_idx[p] = e0;
        }
    }
}

// --- pass 2: per-row register accumulation, fp16 gathers ---------------------

__global__ __launch_bounds__(256) void k_accum_h(
    const __half2* __restrict__ xh, const int* __restrict__ counts,
    const int2* __restrict__ pairs, float* __restrict__ out, int N)
{
    long tid = (long)blockIdx.x * 256 + threadIdx.x;
    int row = (int)(tid >> 5);
    if (row >= N) return;
    int q = (int)(tid & 31);

    int cnt = counts[row];
    if (cnt > CAP) cnt = CAP;

    const int4* prow = reinterpret_cast<const int4*>(pairs + (size_t)row * CAP);
    int s[CAP]; float wv[CAP];
    #pragma unroll
    for (int r2 = 0; r2 < CAP / 2; ++r2) {
        int4 pk = prow[r2];
        s[2 * r2]     = pk.x; wv[2 * r2]     = __int_as_float(pk.y);
        s[2 * r2 + 1] = pk.z; wv[2 * r2 + 1] = __int_as_float(pk.w);
    }
    #pragma unroll
    for (int r = 0; r < CAP; ++r)
        if (r >= cnt) wv[r] = 0.f;          // sanitize poison slots

    // Independent predicated gathers: 8B/lane = 4 halves (channels 4q..4q+3).
    const uint2* x2 = reinterpret_cast<const uint2*>(xh);
    uint2 g[CAP];
    #pragma unroll
    for (int r = 0; r < CAP; ++r) {
        g[r] = make_uint2(0u, 0u);
        if (r < cnt) g[r] = x2[((long)s[r] << 5) + q];
    }
    float4 acc = make_float4(0.f, 0.f, 0.f, 0.f);
    #pragma unroll
    for (int r = 0; r < CAP; ++r) {
        float2 f01 = __half22float2(*reinterpret_cast<__half2*>(&g[r].x));
        float2 f23 = __half22float2(*reinterpret_cast<__half2*>(&g[r].y));
        acc.x += wv[r] * f01.x; acc.y += wv[r] * f01.y;
        acc.z += wv[r] * f23.x; acc.w += wv[r] * f23.y;
    }
    reinterpret_cast<float4*>(out)[((long)row << 5) + q] = acc;
}

// f32 accum (fallback when ws can't hold xh) — proven R4 kernel.
__global__ __launch_bounds__(256) void k_accum_f(
    const float* __restrict__ x, const int* __restrict__ counts,
    const int2* __restrict__ pairs, float* __restrict__ out, int N)
{
    long tid = (long)blockIdx.x * 256 + threadIdx.x;
    int row = (int)(tid >> 5);
    if (row >= N) return;
    int q = (int)(tid & 31);
    int cnt = counts[row];
    if (cnt > CAP) cnt = CAP;
    const int4* prow = reinterpret_cast<const int4*>(pairs + (size_t)row * CAP);
    int s[CAP]; float wv[CAP];
    #pragma unroll
    for (int r2 = 0; r2 < CAP / 2; ++r2) {
        int4 pk = prow[r2];
        s[2 * r2]     = pk.x; wv[2 * r2]     = __int_as_float(pk.y);
        s[2 * r2 + 1] = pk.z; wv[2 * r2 + 1] = __int_as_float(pk.w);
    }
    #pragma unroll
    for (int r = 0; r < CAP; ++r)
        if (r >= cnt) wv[r] = 0.f;
    const float4* x4 = reinterpret_cast<const float4*>(x);
    float4 v[CAP];
    #pragma unroll
    for (int r = 0; r < CAP; ++r) {
        v[r] = make_float4(0.f, 0.f, 0.f, 0.f);
        if (r < cnt) v[r] = x4[((long)s[r] << 5) + q];
    }
    float4 acc = make_float4(0.f, 0.f, 0.f, 0.f);
    #pragma unroll
    for (int r = 0; r < CAP; ++r) {
        acc.x += wv[r] * v[r].x; acc.y += wv[r] * v[r].y;
        acc.z += wv[r] * v[r].z; acc.w += wv[r] * v[r].w;
    }
    reinterpret_cast<float4*>(out)[((long)row << 5) + q] = acc;
}

// --- pass 3: rare rank>=CAP edges (f32 x, exact) -----------------------------

__global__ __launch_bounds__(256) void k_overflow(
    const float* __restrict__ x, const int* __restrict__ src,
    const int* __restrict__ dst, const float* __restrict__ w,
    const int* __restrict__ ovf_cnt, const int* __restrict__ ovf_idx,
    float* __restrict__ out)
{
    int novf = *ovf_cnt;
    if (novf > OVFCAP) novf = OVFCAP;
    long total = (long)novf * 32;
    long stride = (long)gridDim.x * 256;
    for (long i = (long)blockIdx.x * 256 + threadIdx.x; i < total; i += stride) {
        int k = (int)(i >> 5);
        int q = (int)(i & 31);
        int e = ovf_idx[k];
        float ww = w[e];
        float4 v = reinterpret_cast<const float4*>(x)[((long)src[e] << 5) + q];
        float* o = out + ((long)dst[e] << 7) + (q << 2);
        atomicAdd(o + 0, v.x * ww); atomicAdd(o + 1, v.y * ww);
        atomicAdd(o + 2, v.z * ww); atomicAdd(o + 3, v.w * ww);
    }
}

// --- fallback: R2 atomic baseline (ws too small) -----------------------------

__global__ __launch_bounds__(256) void unpool_scatter_atomic(
    const float* __restrict__ x, const int* __restrict__ src_idx,
    const int* __restrict__ dst_idx, const float* __restrict__ edge_attr,
    float* __restrict__ out, int E)
{
    long tid = (long)blockIdx.x * (long)blockDim.x + threadIdx.x;
    int e = (int)(tid >> 5);
    if (e >= E) return;
    int q = (int)(tid & 31);
    float w = edge_attr[e];
    const float4 v = reinterpret_cast<const float4*>(x)[((long)src_idx[e] << 5) + q];
    float* o = out + ((long)dst_idx[e] << 7) + (q << 2);
    atomicAdd(o + 0, v.x * w); atomicAdd(o + 1, v.y * w);
    atomicAdd(o + 2, v.z * w); atomicAdd(o + 3, v.w * w);
}

extern "C" void kernel_launch(void* const* d_in, const int* in_sizes, int n_in,
                              void* d_out, int out_size, void* d_ws, size_t ws_size,
                              hipStream_t stream) {
    const float* x        = (const float*)d_in[0];
    const int*   src_idx  = (const int*)d_in[1];
    const int*   dst_idx  = (const int*)d_in[2];
    const float* edge_att = (const float*)d_in[3];
    float*       out      = (float*)d_out;

    const int E  = in_sizes[1];         // 800000
    const int C  = 128;
    const int N  = out_size / C;        // 200000
    const int NC = in_sizes[0] / C;     // 50000 coarse rows

    // ws: counts | ovf_cnt | ovf_idx | pairs | xh
    size_t off_ovf    = ((size_t)N * 4 + 15) & ~(size_t)15;
    size_t off_ovfidx = off_ovf + 16;
    size_t off_pairs  = (off_ovfidx + (size_t)OVFCAP * 4 + 15) & ~(size_t)15;
    size_t off_xh     = off_pairs + (size_t)N * CAP * 8;
    size_t need_base  = off_xh;
    size_t need_h     = off_xh + (size_t)NC * C * 2;

    char* ws = (char*)d_ws;
    if (ws_size < need_base) {
        hipMemsetAsync(d_out, 0, (size_t)out_size * sizeof(float), stream);
        long total = (long)E * 32;
        unpool_scatter_atomic<<<dim3((unsigned)((total + 255) / 256)), dim3(256),
                                0, stream>>>(x, src_idx, dst_idx, edge_att, out, E);
        return;
    }

    int*     counts  = (int*)(ws);
    int*     ovf_cnt = (int*)(ws + off_ovf);
    int*     ovf_idx = (int*)(ws + off_ovfidx);
    int2*    pairs   = (int2*)(ws + off_pairs);
    __half2* xh      = (__half2*)(ws + off_xh);
    const bool use_h = (ws_size >= need_h);

    // Zero counts + overflow counter (~0.8MB).
    hipMemsetAsync(ws, 0, off_ovf + 16, stream);

    if (use_h) {
        int nf4 = NC * C / 4;
        k_convert<<<dim3((nf4 + 255) / 256), dim3(256), 0, stream>>>(x, xh, nf4);
    }

    int nthr = (E + 1) / 2;
    k_scatter<<<dim3((nthr + 255) / 256), dim3(256), 0, stream>>>(
        src_idx, dst_idx, edge_att, counts, ovf_cnt, ovf_idx, pairs, E);

    long total = (long)N * 32;
    if (use_h) {
        k_accum_h<<<dim3((unsigned)((total + 255) / 256)), dim3(256), 0, stream>>>(
            xh, counts, pairs, out, N);
    } else {
        k_accum_f<<<dim3((unsigned)((total + 255) / 256)), dim3(256), 0, stream>>>(
            x, counts, pairs, out, N);
    }

    k_overflow<<<dim3(256), dim3(256), 0, stream>>>(
        x, src_idx, dst_idx, edge_att, ovf_cnt, ovf_idx, out);
}